// Round 7
// baseline (223.607 us; speedup 1.0000x reference)
//
#include <hip/hip_runtime.h>

#define H 1024
#define W 1024
#define NPIX (H*W)
#define BATCH 4
#define TW 64
#define TH 16
#define NT 4
#define SLOTS 32
#define PART_FLOATS (BATCH*15*SLOTS)
#define R1 140   // pass1 LDS row stride (floats): 132 used + 8 pad; 140%32=12 -> balanced banks, rows 16B-aligned
#define R3 68    // pass3 LDS row stride (floats): 66 used + 2 pad; 68%32=4 -> balanced banks, rows 16B-aligned

// ---------------- pass1: partials (15 reduction scalars per batch) ----------------
__global__ __launch_bounds__(256) void pass1(
    const float* __restrict__ x, const float* __restrict__ fhigh,
    const float* __restrict__ qCw, const float* __restrict__ qdw,
    const float* __restrict__ kCw, const float* __restrict__ kdw,
    float* __restrict__ partials)
{
  __shared__ alignas(16) float m[3 * 18 * R1];  // interleaved q,k mids: idx=(c*18+hy)*R1 + 2*hx + s
  __shared__ float rb[4][15];

  const int tid = threadIdx.x;
  const int wv = tid >> 6, ln = tid & 63;
  const int tx = tid & 15, ty = tid >> 4;
  const int tileX = blockIdx.x, tY = blockIdx.y, b = blockIdx.z;
  const int cx0 = tileX * TW;

  float wqc[9], wkc[9], wqd[27], wkd[27];
  #pragma unroll
  for (int i = 0; i < 9; i++)  { wqc[i] = qCw[i]; wkc[i] = kCw[i]; }
  #pragma unroll
  for (int i = 0; i < 27; i++) { wqd[i] = qdw[i]; wkd[i] = kdw[i]; }

  const float* fb = fhigh + (size_t)b * 3 * NPIX;
  const float* xb = x + (size_t)b * NPIX * 3;

  float acc[15];
  #pragma unroll
  for (int i = 0; i < 15; i++) acc[i] = 0.f;

  for (int t = 0; t < NT; ++t) {
    const int row0 = (tY * NT + t) * TH;
    __syncthreads();   // protect previous tile's LDS reads

    // ---- stage: wave wv handles rows hy = wv, wv+4, ... ; lane = halo column ----
    #pragma unroll
    for (int kk = 0; kk < 5; ++kk) {
      const int hy = wv + 4 * kk;
      if (hy < 18) {
        const int gy = row0 - 1 + hy;
        const bool rv = (unsigned)gy < (unsigned)H;
        #pragma unroll
        for (int e = 0; e < 2; ++e) {
          if (e == 0 || ln < 2) {
            const int hx = e ? (64 + ln) : ln;
            const int gx = cx0 - 1 + hx;
            float f0=0.f,f1=0.f,f2=0.f,x0=0.f,x1=0.f,x2=0.f;
            if (rv && (unsigned)gx < (unsigned)W) {
              const float* fr = fb + (size_t)gy * W + gx;
              f0 = fr[0]; f1 = fr[NPIX]; f2 = fr[2*NPIX];
              const float* xr = xb + ((size_t)gy * W + gx) * 3;
              if (gx < W - 1) { float4 v = *(const float4*)xr; x0=v.x; x1=v.y; x2=v.z; }
              else            { x0 = xr[0]; x1 = xr[1]; x2 = xr[2]; }
            }
            #pragma unroll
            for (int c = 0; c < 3; c++) {
              float2 p;
              p.x = wqc[c*3+0]*f0 + wqc[c*3+1]*f1 + wqc[c*3+2]*f2;   // q mid
              p.y = wkc[c*3+0]*x0 + wkc[c*3+1]*x1 + wkc[c*3+2]*x2;   // k mid
              *(float2*)&m[(c*18 + hy)*R1 + 2*hx] = p;
            }
          }
        }
      }
    }
    __syncthreads();

    // ---- consume: thread (tx,ty) -> 4 px at row row0+ty, cols cx0+4tx.. ----
    float qv[3][4], kv[3][4];
    #pragma unroll
    for (int c = 0; c < 3; c++)
      #pragma unroll
      for (int i = 0; i < 4; i++) { qv[c][i] = 0.f; kv[c][i] = 0.f; }

    #pragma unroll
    for (int dy = 0; dy < 3; dy++) {
      const int hy = ty + dy;
      #pragma unroll
      for (int c = 0; c < 3; c++) {
        const float* mr = &m[(c*18 + hy)*R1 + 8*tx];
        const float4 A  = *(const float4*)(mr);       // q(hx=4tx) k | q(4tx+1) k
        const float4 Bv = *(const float4*)(mr + 4);   // q(4tx+2) k | q(4tx+3) k
        const float4 Cv = *(const float4*)(mr + 8);   // q(4tx+4) k | q(4tx+5) k
        const float a0=wqd[c*9+dy*3+0], a1=wqd[c*9+dy*3+1], a2=wqd[c*9+dy*3+2];
        qv[c][0] += a0*A.x  + a1*A.z  + a2*Bv.x;
        qv[c][1] += a0*A.z  + a1*Bv.x + a2*Bv.z;
        qv[c][2] += a0*Bv.x + a1*Bv.z + a2*Cv.x;
        qv[c][3] += a0*Bv.z + a1*Cv.x + a2*Cv.z;
        const float b0=wkd[c*9+dy*3+0], b1=wkd[c*9+dy*3+1], b2=wkd[c*9+dy*3+2];
        kv[c][0] += b0*A.y  + b1*A.w  + b2*Bv.y;
        kv[c][1] += b0*A.w  + b1*Bv.y + b2*Bv.w;
        kv[c][2] += b0*Bv.y + b1*Bv.w + b2*Cv.y;
        kv[c][3] += b0*Bv.w + b1*Cv.y + b2*Cv.w;
      }
    }
    #pragma unroll
    for (int i = 0; i < 4; i++) {
      #pragma unroll
      for (int c = 0; c < 3; c++) { acc[c] += qv[c][i]*qv[c][i]; acc[3+c] += kv[c][i]*kv[c][i]; }
      #pragma unroll
      for (int c = 0; c < 3; c++)
        #pragma unroll
        for (int d = 0; d < 3; d++) acc[6 + c*3 + d] += qv[c][i]*kv[d][i];
    }
  }

  #pragma unroll
  for (int off = 32; off >= 1; off >>= 1)
    #pragma unroll
    for (int i = 0; i < 15; i++)
      acc[i] += __shfl_xor(acc[i], off, 64);

  if (ln == 0) {
    #pragma unroll
    for (int i = 0; i < 15; i++) rb[wv][i] = acc[i];
  }
  __syncthreads();
  if (tid < 15) {
    float s = rb[0][tid] + rb[1][tid] + rb[2][tid] + rb[3][tid];
    const int slot = (tY * 16 + tileX) & (SLOTS - 1);
    atomicAdd(&partials[(b * 15 + tid) * SLOTS + slot], s);
  }
}

// ---------------- pass3: recompute kv, apply folded softmax-proj ----------------
__global__ __launch_bounds__(256) void pass3(
    const float* __restrict__ x,
    const float* __restrict__ kCw, const float* __restrict__ kdw,
    const float* __restrict__ partials,
    const float* __restrict__ proj_w, const float* __restrict__ proj_b,
    const float* __restrict__ temperature,
    float* __restrict__ out)
{
  __shared__ alignas(16) float mk[3 * 18 * R3];  // k mids: idx=(c*18+hy)*R3 + hx

  const int tid = threadIdx.x;
  const int wv = tid >> 6, ln = tid & 63;
  const int tx = tid & 15, ty = tid >> 4;
  const int tileX = blockIdx.x, tY = blockIdx.y, b = blockIdx.z;
  const int cx0 = tileX * TW;

  // ---- folded pass2 (uniform per block) ----
  float sums[15];
  #pragma unroll
  for (int i = 0; i < 15; i++) {
    float s = 0.f;
    #pragma unroll 8
    for (int sl = 0; sl < SLOTS; sl++) s += partials[(b * 15 + i) * SLOTS + sl];
    sums[i] = s;
  }
  float qn[3], kn[3];
  #pragma unroll
  for (int c = 0; c < 3; c++) { qn[c] = sqrtf(sums[c]); kn[c] = sqrtf(sums[3 + c]); }
  const float tmp = temperature[0];
  float attn[3][3];
  #pragma unroll
  for (int c = 0; c < 3; c++) {
    float lg[3];
    #pragma unroll
    for (int d = 0; d < 3; d++)
      lg[d] = sums[6 + c*3 + d] / fmaxf(qn[c], 1e-12f) / fmaxf(kn[d], 1e-12f) * tmp;
    float mx = fmaxf(lg[0], fmaxf(lg[1], lg[2]));
    float e0 = expf(lg[0]-mx), e1 = expf(lg[1]-mx), e2 = expf(lg[2]-mx);
    float inv = 1.f / (e0 + e1 + e2);
    attn[c][0] = e0*inv; attn[c][1] = e1*inv; attn[c][2] = e2*inv;
  }
  float M[3][3];
  #pragma unroll
  for (int o = 0; o < 3; o++)
    #pragma unroll
    for (int d = 0; d < 3; d++)
      M[o][d] = proj_w[o*3+0]*attn[0][d] + proj_w[o*3+1]*attn[1][d] + proj_w[o*3+2]*attn[2][d];
  const float pb0 = proj_b[0], pb1 = proj_b[1], pb2 = proj_b[2];

  float wkc[9], wkd[27];
  #pragma unroll
  for (int i = 0; i < 9; i++)  wkc[i] = kCw[i];
  #pragma unroll
  for (int i = 0; i < 27; i++) wkd[i] = kdw[i];

  const float* xb = x + (size_t)b * NPIX * 3;
  float* ob = out + (size_t)b * NPIX * 3;

  for (int t = 0; t < NT; ++t) {
    const int row0 = (tY * NT + t) * TH;
    __syncthreads();

    #pragma unroll
    for (int kk = 0; kk < 5; ++kk) {
      const int hy = wv + 4 * kk;
      if (hy < 18) {
        const int gy = row0 - 1 + hy;
        const bool rv = (unsigned)gy < (unsigned)H;
        #pragma unroll
        for (int e = 0; e < 2; ++e) {
          if (e == 0 || ln < 2) {
            const int hx = e ? (64 + ln) : ln;
            const int gx = cx0 - 1 + hx;
            float x0=0.f,x1=0.f,x2=0.f;
            if (rv && (unsigned)gx < (unsigned)W) {
              const float* xr = xb + ((size_t)gy * W + gx) * 3;
              if (gx < W - 1) { float4 v = *(const float4*)xr; x0=v.x; x1=v.y; x2=v.z; }
              else            { x0 = xr[0]; x1 = xr[1]; x2 = xr[2]; }
            }
            #pragma unroll
            for (int c = 0; c < 3; c++)
              mk[(c*18 + hy)*R3 + hx] = wkc[c*3+0]*x0 + wkc[c*3+1]*x1 + wkc[c*3+2]*x2;
          }
        }
      }
    }
    __syncthreads();

    float kv[3][4];
    #pragma unroll
    for (int c = 0; c < 3; c++)
      #pragma unroll
      for (int i = 0; i < 4; i++) kv[c][i] = 0.f;

    #pragma unroll
    for (int dy = 0; dy < 3; dy++) {
      const int hy = ty + dy;
      #pragma unroll
      for (int c = 0; c < 3; c++) {
        const float* mr = &mk[(c*18 + hy)*R3 + 4*tx];
        const float4 A  = *(const float4*)(mr);       // k(hx=4tx .. 4tx+3)
        const float4 Bv = *(const float4*)(mr + 4);   // k(4tx+4 .. 4tx+7)
        const float b0=wkd[c*9+dy*3+0], b1=wkd[c*9+dy*3+1], b2=wkd[c*9+dy*3+2];
        kv[c][0] += b0*A.x + b1*A.y  + b2*A.z;
        kv[c][1] += b0*A.y + b1*A.z  + b2*A.w;
        kv[c][2] += b0*A.z + b1*A.w  + b2*Bv.x;
        kv[c][3] += b0*A.w + b1*Bv.x + b2*Bv.y;
      }
    }

    float o[4][3];
    #pragma unroll
    for (int i = 0; i < 4; i++) {
      o[i][0] = M[0][0]*kv[0][i] + M[0][1]*kv[1][i] + M[0][2]*kv[2][i] + pb0;
      o[i][1] = M[1][0]*kv[0][i] + M[1][1]*kv[1][i] + M[1][2]*kv[2][i] + pb1;
      o[i][2] = M[2][0]*kv[0][i] + M[2][1]*kv[1][i] + M[2][2]*kv[2][i] + pb2;
    }
    float* op = ob + ((size_t)(row0 + ty) * W + cx0 + 4*tx) * 3;
    float4 w0, w1, w2;
    w0.x = o[0][0]; w0.y = o[0][1]; w0.z = o[0][2]; w0.w = o[1][0];
    w1.x = o[1][1]; w1.y = o[1][2]; w1.z = o[2][0]; w1.w = o[2][1];
    w2.x = o[2][2]; w2.y = o[3][0]; w2.z = o[3][1]; w2.w = o[3][2];
    *(float4*)(op)     = w0;
    *(float4*)(op + 4) = w1;
    *(float4*)(op + 8) = w2;
  }
}

extern "C" void kernel_launch(void* const* d_in, const int* in_sizes, int n_in,
                              void* d_out, int out_size, void* d_ws, size_t ws_size,
                              hipStream_t stream) {
  const float* x     = (const float*)d_in[0];
  const float* fhigh = (const float*)d_in[1];
  const float* qCw   = (const float*)d_in[2];
  const float* qdw   = (const float*)d_in[3];
  const float* kCw   = (const float*)d_in[4];
  const float* kdw   = (const float*)d_in[5];
  const float* pw    = (const float*)d_in[6];
  const float* pb    = (const float*)d_in[7];
  const float* temp  = (const float*)d_in[8];
  float* out = (float*)d_out;

  float* partials = (float*)d_ws;
  hipMemsetAsync(partials, 0, PART_FLOATS * sizeof(float), stream);

  dim3 grid(W / TW, H / (TH * NT), BATCH);   // 16 x 16 x 4
  pass1<<<grid, 256, 0, stream>>>(x, fhigh, qCw, qdw, kCw, kdw, partials);
  pass3<<<grid, 256, 0, stream>>>(x, kCw, kdw, partials, pw, pb, temp, out);
}